// Round 4
// baseline (167.877 us; speedup 1.0000x reference)
//
#include <hip/hip_runtime.h>
#include <math.h>

// ---------------------------------------------------------------------------
// TropicalMLP: h_i = logsumexp_j(x_j + w_ij) + b_i = log(sum_j e^x_j e^w_ij)+b_i
// Row-independent network: one block owns ONE batch row, runs all 3 layers +
// 2 tropical-LNs with only __syncthreads(). Two dispatches.
// fp8 e4m3 operands via mfma_f32_16x16x32_fp8_fp8.
// Scaling keeps fp8 normal-range: layer1 A = 4*exp(x) (+ln4 cancels in LN1
// median); layers2/3 A = 64*exp(y-cm) (+ln64 cancels in LN2; subtracted in
// final epilogue). B = exp(w) in [0.6,1.6] needs no scale.
// Weights pre-exp'd + permuted to MFMA-fragment order (512B-coalesced loads).
// R8: B-prefetch for each layer hoisted ABOVE the preceding barrier.
// R9: bitonic sort as compact runtime loops (I-footprint fix; -10%).
// R10: 2 blocks/CU TLP (-11%).  R11: LN on all waves (fused < 40us).
// R12: TLP TO HW MAX. Still latency-bound (all pipes <25%): 1 row/block x
// 1024 blocks = 4 blocks/CU = 32 waves/CU (hardware max; VGPR<=64 enforced
// via __launch_bounds__(512,8), was 60). 8 interleaved chains per SIMD fill
// the vmcnt/barrier/shuffle stalls. A-row dup 16x in MFMA slot -- free at 9%
// MfmaUtil. LN: 8 waves x 1 elem/lane, 39 single-shuffle rounds + 6 LDS
// exchange rounds (jj>=64), math identical.
// ---------------------------------------------------------------------------

typedef float v4f __attribute__((ext_vector_type(4)));

#define ELS_B 528                  // bytes per LDS A-row (16B pad)
#define LN64f 4.1588830833596715f  // ln(64)

__device__ __forceinline__ int pk4_fp8(float a, float b, float c, float d) {
    int p = __builtin_amdgcn_cvt_pk_fp8_f32(a, b, 0, 0);      // bytes 0,1
    p = __builtin_amdgcn_cvt_pk_fp8_f32(c, d, p, 1);          // bytes 2,3
    return p;
}

// D1: exp + fp8 + fragment reorder. Global 16-col tile S, k-step t (32 k),
// lane l = q*16+r:  Ef[(S*16+t)*512 + l*8 + j] = fp8(exp(W[S*16+r][t*32+q*8+j]))
// S: 0..31 -> w1, 32..63 -> w2, 64..79 -> w3 (contiguous per layer, in bytes).
__global__ __launch_bounds__(256) void expW_frag(const float* __restrict__ w1,
                                                 const float* __restrict__ w2,
                                                 const float* __restrict__ w3,
                                                 uint8_t* __restrict__ Ef) {
    int u = blockIdx.x * 256 + threadIdx.x;          // 0..81919 (320 blocks)
    int lane = u & 63, t = (u >> 6) & 15, S = u >> 10;
    int r = lane & 15, q = lane >> 4;
    const float* w; int tile;
    if (S < 32)      { w = w1; tile = S; }
    else if (S < 64) { w = w2; tile = S - 32; }
    else             { w = w3; tile = S - 64; }
    const float* src = w + (tile * 16 + r) * 512 + t * 32 + q * 8;
    float4 a = *reinterpret_cast<const float4*>(src);
    float4 b = *reinterpret_cast<const float4*>(src + 4);
    int2 o;
    o.x = pk4_fp8(__expf(a.x), __expf(a.y), __expf(a.z), __expf(a.w));
    o.y = pk4_fp8(__expf(b.x), __expf(b.y), __expf(b.z), __expf(b.w));
    *reinterpret_cast<int2*>(Ef + u * 8) = o;
}

// Preload whole A operand (1 row dup'd 16x in the 16-row slot) for all 16
// k-steps: 16 x ds_read_b64 (same addr within a q-group -> LDS broadcast).
__device__ __forceinline__ void load_areg(const uint8_t* Els, int lane, long* areg) {
    const uint8_t* ap = Els + ((lane >> 4) & 3) * 8;
#pragma unroll
    for (int t = 0; t < 16; ++t)
        areg[t] = *reinterpret_cast<const long*>(ap + t * 32);
}

// Issue the first 8 k-steps of a layer's B stream (kept in flight across the
// following barrier / LN — this is the latency-hiding hoist).
template <int NSUB>
__device__ __forceinline__ void prefetchB(const uint8_t* __restrict__ bp,
                                          int s0, long bb[8][4]) {
#pragma unroll
    for (int p = 0; p < 8; ++p)
#pragma unroll
        for (int s = 0; s < NSUB; ++s)
            bb[p][s] = *reinterpret_cast<const long*>(bp + ((s0 + s) * 16 + p) * 512);
}

// C[16(dup rows) x NSUB*16 cols] over K=512, fp8 MFMA, consuming the
// prefetched pipe and rolling it forward (depth 8).
template <int NSUB>
__device__ __forceinline__ void gemm_body(const uint8_t* __restrict__ bp,
                                          int s0, const long* areg,
                                          long bb[8][4], v4f* acc) {
#pragma unroll
    for (int s = 0; s < NSUB; ++s) acc[s] = (v4f){0.f, 0.f, 0.f, 0.f};
#pragma unroll
    for (int t = 0; t < 16; ++t) {
        long a = areg[t];
        long bcur[NSUB];
#pragma unroll
        for (int s = 0; s < NSUB; ++s) bcur[s] = bb[t & 7][s];
        if (t < 8) {
#pragma unroll
            for (int s = 0; s < NSUB; ++s)
                bb[t & 7][s] =
                    *reinterpret_cast<const long*>(bp + ((s0 + s) * 16 + t + 8) * 512);
        }
#pragma unroll
        for (int s = 0; s < NSUB; ++s)
            acc[s] = __builtin_amdgcn_mfma_f32_16x16x32_fp8_fp8(a, bcur[s],
                                                                acc[s], 0, 0, 0);
    }
}

// Tropical-LN on the block's single row, all 8 waves, 1 element/lane
// (e = w*64+lane): exact order stats via bitonic sort; jj>=64 rounds exchange
// through hb (LDS, h kept in regs); relu; subtract rowmax; 64*exp -> fp8.
// MUST be called by all 8 waves (internal __syncthreads).
__device__ __forceinline__ void ln_row8(float* hb,
                                        const float* __restrict__ lw,
                                        const float* __restrict__ lb,
                                        uint8_t* Els, float* crow,
                                        float* cmx,               // [8]
                                        int w, int lane) {
    const int e = w * 64 + lane;
    float lwv = lw[e], lbv = lb[e];
    float h = hb[e];
    float v = h;

    // Stages k = 2..64: every round within a wave (single shfl each).
#pragma clang loop unroll(disable)
    for (int k = 2; k <= 64; k <<= 1) {
#pragma clang loop unroll(disable)
        for (int jj = (k >> 1); jj >= 1; jj >>= 1) {
            float p = __shfl_xor(v, jj);
            bool keepmin = (((e & k) == 0) == ((lane & jj) == 0));
            v = keepmin ? fminf(v, p) : fmaxf(v, p);
        }
    }
    // Stages k = 128..512: jj>=64 via LDS exchange, rest in-wave.
#pragma clang loop unroll(disable)
    for (int k = 128; k <= 512; k <<= 1) {
#pragma clang loop unroll(disable)
        for (int jj = (k >> 1); jj >= 64; jj >>= 1) {
            __syncthreads();
            hb[e] = v;
            __syncthreads();
            float p = hb[e ^ jj];
            bool keepmin = (((e & k) == 0) == ((e & jj) == 0));
            v = keepmin ? fminf(v, p) : fmaxf(v, p);
        }
#pragma clang loop unroll(disable)
        for (int jj = 32; jj >= 1; jj >>= 1) {
            float p = __shfl_xor(v, jj);
            bool keepmin = (((e & k) == 0) == ((lane & jj) == 0));
            v = keepmin ? fminf(v, p) : fmaxf(v, p);
        }
    }
    // Write-back + order-stat broadcast reads.
    __syncthreads();
    hb[e] = v;
    __syncthreads();
    float s127 = hb[127], s128 = hb[128], med = hb[255];
    float s383 = hb[383], s384 = hb[384];
    float q25 = s127 + 0.75f * (s128 - s127);
    float q75 = s383 + 0.25f * (s384 - s383);
    float inv = 1.0f / fmaxf(q75 - q25, 1e-6f);

    float y = fmaxf((h - med) * inv * lwv + lbv, 0.0f);
    float cm = y;
#pragma unroll
    for (int s = 32; s > 0; s >>= 1) cm = fmaxf(cm, __shfl_xor(cm, s));
    if (lane == 0) cmx[w] = cm;
    __syncthreads();
    cm = fmaxf(fmaxf(fmaxf(cmx[0], cmx[1]), fmaxf(cmx[2], cmx[3])),
               fmaxf(fmaxf(cmx[4], cmx[5]), fmaxf(cmx[6], cmx[7])));

    int p = __builtin_amdgcn_cvt_pk_fp8_f32(64.0f * __expf(y - cm), 0.0f, 0, 0);
    Els[e] = (uint8_t)(p & 0xff);
    if (w == 0 && lane == 0) crow[0] = cm;
}

__global__ __launch_bounds__(512, 8) void fused_rows(
    const float* __restrict__ x,
    const float* __restrict__ b1,
    const float* __restrict__ ln1w, const float* __restrict__ ln1b,
    const float* __restrict__ b2,
    const float* __restrict__ ln2w, const float* __restrict__ ln2b,
    const float* __restrict__ b3,
    const uint8_t* __restrict__ Ew,
    float* __restrict__ out)
{
    __shared__ uint8_t Els[ELS_B];             // fp8 activations (1 row)
    __shared__ float hbuf[512];                // pre-LN output / sort scratch
    __shared__ float crow[1];                  // row shift (last LN)
    __shared__ float cmx[8];                   // per-wave max partials

    const int tid = threadIdx.x;
    const int lane = tid & 63;
    const int w = tid >> 6;                    // wave id 0..7
    const int r = lane & 15, q = lane >> 4;
    const int blk = blockIdx.x;                // row blk

    const uint8_t* bp1 = Ew + lane * 8;
    const uint8_t* bp2 = bp1 + 262144;
    const uint8_t* bp3 = bp1 + 524288;

    long bb[8][4];
    long areg[16];
    v4f acc[4];

    // ---- layer-1 B prefetch in flight during the exp(x) prologue ----
    prefetchB<4>(bp1, w * 4, bb);

    // ---- phase 0: A1 = fp8(4*exp(x)) for this block's row ----
    // (+ln4 shift cancels in LN1's median subtraction; keeps fp8 normal-range)
    if (tid < 128) {
        int col = tid * 4;
        float4 a = *reinterpret_cast<const float4*>(x + blk * 512 + col);
        *reinterpret_cast<int*>(&Els[col]) =
            pk4_fp8(4.0f * __expf(a.x), 4.0f * __expf(a.y),
                    4.0f * __expf(a.z), 4.0f * __expf(a.w));
    }
    __syncthreads();

    // ===== layer 1: wave w covers cols w*64..w*64+64 (tiles w*4..w*4+4) =====
    load_areg(Els, lane, areg);
    gemm_body<4>(bp1, w * 4, areg, bb, acc);
    {   // epilogue spread over q-groups: lane group q owns subtile s=q.
        // All 16 C rows identical (A dup'd) -> use reg 0.
        v4f av = (q == 0) ? acc[0] : (q == 1) ? acc[1] : (q == 2) ? acc[2] : acc[3];
        int col = (w * 4 + q) * 16 + r;
        hbuf[col] = __logf(av[0]) + b1[col];
    }
    prefetchB<4>(bp2, w * 4, bb);              // layer-2 B rides over LN1
    __syncthreads();
    ln_row8(hbuf, ln1w, ln1b, Els, crow, cmx, w, lane);
    __syncthreads();

    // ===== layer 2 (uniform ln64 - cm1 shift absorbed by LN2's median) =====
    load_areg(Els, lane, areg);
    gemm_body<4>(bp2, w * 4, areg, bb, acc);
    {
        v4f av = (q == 0) ? acc[0] : (q == 1) ? acc[1] : (q == 2) ? acc[2] : acc[3];
        int col = (w * 4 + q) * 16 + r;
        hbuf[col] = __logf(av[0]) + b2[col];
    }
    prefetchB<2>(bp3, w * 2, bb);              // layer-3 B rides over LN2
    __syncthreads();
    ln_row8(hbuf, ln2w, ln2b, Els, crow, cmx, w, lane);
    __syncthreads();

    // ===== layer 3 (N=256, tiles w*2..w*2+1): out = log(acc)+cm2-ln64+b3 =====
    load_areg(Els, lane, areg);
    gemm_body<2>(bp3, w * 2, areg, bb, acc);
    if (q < 2) {
        v4f av = (q == 0) ? acc[0] : acc[1];
        int col = (w * 2 + q) * 16 + r;
        out[blk * 256 + col] = __logf(av[0]) + crow[0] + b3[col] - LN64f;
    }
}

extern "C" void kernel_launch(void* const* d_in, const int* in_sizes, int n_in,
                              void* d_out, int out_size, void* d_ws, size_t ws_size,
                              hipStream_t stream) {
    const float* x    = (const float*)d_in[0];
    const float* w1   = (const float*)d_in[1];
    const float* b1   = (const float*)d_in[2];
    const float* ln1w = (const float*)d_in[3];
    const float* ln1b = (const float*)d_in[4];
    const float* w2   = (const float*)d_in[5];
    const float* b2   = (const float*)d_in[6];
    const float* ln2w = (const float*)d_in[7];
    const float* ln2b = (const float*)d_in[8];
    const float* w3   = (const float*)d_in[9];
    const float* b3   = (const float*)d_in[10];
    float* out = (float*)d_out;

    uint8_t* Ew = (uint8_t*)d_ws;              // 655360 B fp8 = 640 KB

    expW_frag<<<320, 256, 0, stream>>>(w1, w2, w3, Ew);
    fused_rows<<<1024, 512, 0, stream>>>(x, b1, ln1w, ln1b, b2, ln2w, ln2b,
                                         b3, Ew, out);
}

// Round 5
// 115.331 us; speedup vs baseline: 1.4556x; 1.4556x over previous
//
#include <hip/hip_runtime.h>
#include <math.h>

// ---------------------------------------------------------------------------
// TropicalMLP, R13: LAYERED DECOMPOSITION (vs R0-R11 monolithic fused chain).
// R12 post-mortem: raising fused TLP to 4 blocks/CU forced a 64-VGPR budget
// -> bb[8][4] spilled -> 140MB scratch writes, 95us. Fused TLP is capped at
// 2 blocks/CU (~40us, R11), all pipes <25% busy: the serial 6-phase chain is
// the structural limit. So: 6 short kernels, each fully parallel:
//   prep (exp W1/W2/W3 + 4*exp(x), fp8, MFMA-fragment order)
//   gemm_h L1 -> ln_rows LN1 -> gemm_h L2 -> ln_rows LN2 -> gemm_out L3
// GEMM waves now compute 16 REAL rows per MFMA (no 16x duplication); LN is
// one wave per row, zero barriers, R9's verified in-register bitonic.
// Same math/scaling as R11: layer1 A=4*exp(x) (+ln4 cancels in LN1 median);
// layers2/3 A=64*exp(y-cm) (+ln64-cm cancels in LN2 median / subtracted in
// final epilogue). B=exp(w) in [0.6,1.6]. Bit-identical output to R11.
// ---------------------------------------------------------------------------

typedef float v4f __attribute__((ext_vector_type(4)));

#define LN64f 4.1588830833596715f  // ln(64)

__device__ __forceinline__ int pk4_fp8(float a, float b, float c, float d) {
    int p = __builtin_amdgcn_cvt_pk_fp8_f32(a, b, 0, 0);      // bytes 0,1
    p = __builtin_amdgcn_cvt_pk_fp8_f32(c, d, p, 1);          // bytes 2,3
    return p;
}

// prep: fp8 exp, MFMA-fragment order. 16-col tile "tile", k-step t (32 k),
// lane l=q*16+r: dst[(tile*16+t)*512 + l*8 + j] = fp8(sc*exp(M[tile*16+r][t*32+q*8+j]))
// u-space S: 0..31 w1 | 32..63 w2 | 64..79 w3 | 80..143 x (sc=4).
__global__ __launch_bounds__(256) void prep_frag(const float* __restrict__ w1,
                                                 const float* __restrict__ w2,
                                                 const float* __restrict__ w3,
                                                 const float* __restrict__ x,
                                                 uint8_t* __restrict__ Ew,
                                                 uint8_t* __restrict__ Ax) {
    int u = blockIdx.x * 256 + threadIdx.x;          // 0..147455 (576 blocks)
    int lane = u & 63, t = (u >> 6) & 15, S = u >> 10;
    int r = lane & 15, q = lane >> 4;
    const float* m; int tile; uint8_t* dst; float sc;
    if (S < 32)      { m = w1; tile = S;      dst = Ew;          sc = 1.0f; }
    else if (S < 64) { m = w2; tile = S - 32; dst = Ew + 262144; sc = 1.0f; }
    else if (S < 80) { m = w3; tile = S - 64; dst = Ew + 524288; sc = 1.0f; }
    else             { m = x;  tile = S - 80; dst = Ax;          sc = 4.0f; }
    const float* src = m + (tile * 16 + r) * 512 + t * 32 + q * 8;
    float4 a = *reinterpret_cast<const float4*>(src);
    float4 b = *reinterpret_cast<const float4*>(src + 4);
    int2 o;
    o.x = pk4_fp8(sc * __expf(a.x), sc * __expf(a.y),
                  sc * __expf(a.z), sc * __expf(a.w));
    o.y = pk4_fp8(sc * __expf(b.x), sc * __expf(b.y),
                  sc * __expf(b.z), sc * __expf(b.w));
    *reinterpret_cast<int2*>(dst + (tile * 16 + t) * 512 + lane * 8) = o;
}

// One wave: C[16 real rows x 4*16 cols] over K=512, fp8 MFMA, rolling
// depth-8 B prefetch (proven R8 pipeline). ap = Af + m*8192 + lane*8,
// bp = Bf + lane*8, subtile base s0.
__device__ __forceinline__ void gemm_k512(const uint8_t* __restrict__ ap,
                                          const uint8_t* __restrict__ bp,
                                          int s0, v4f* acc) {
    long areg[16];
    long bb[8][4];
#pragma unroll
    for (int t = 0; t < 16; ++t)
        areg[t] = *reinterpret_cast<const long*>(ap + t * 512);
#pragma unroll
    for (int p = 0; p < 8; ++p)
#pragma unroll
        for (int s = 0; s < 4; ++s)
            bb[p][s] = *reinterpret_cast<const long*>(bp + ((s0 + s) * 16 + p) * 512);
#pragma unroll
    for (int s = 0; s < 4; ++s) acc[s] = (v4f){0.f, 0.f, 0.f, 0.f};
#pragma unroll
    for (int t = 0; t < 16; ++t) {
        long a = areg[t];
        long bcur[4];
#pragma unroll
        for (int s = 0; s < 4; ++s) bcur[s] = bb[t & 7][s];
        if (t < 8) {
#pragma unroll
            for (int s = 0; s < 4; ++s)
                bb[t & 7][s] =
                    *reinterpret_cast<const long*>(bp + ((s0 + s) * 16 + t + 8) * 512);
        }
#pragma unroll
        for (int s = 0; s < 4; ++s)
            acc[s] = __builtin_amdgcn_mfma_f32_16x16x32_fp8_fp8(a, bcur[s],
                                                                acc[s], 0, 0, 0);
    }
}

// Layers 1/2: h[row][col] = log(acc) + bias[col].  Wave W=blockIdx: m=W>>3
// (M-tile), n64=W&7 (64-col group). Grid 512 x 64 threads.
__global__ __launch_bounds__(64) void gemm_h(const uint8_t* __restrict__ Af,
                                             const uint8_t* __restrict__ Bf,
                                             const float* __restrict__ bias,
                                             float* __restrict__ h) {
    int Wv = blockIdx.x;
    int m = Wv >> 3, n64 = Wv & 7;
    int lane = threadIdx.x;
    int r = lane & 15, q = lane >> 4;
    v4f acc[4];
    gemm_k512(Af + m * 8192 + lane * 8, Bf + lane * 8, n64 * 4, acc);
#pragma unroll
    for (int s = 0; s < 4; ++s) {
        int col = (n64 * 4 + s) * 16 + r;
        float bv = bias[col];
#pragma unroll
        for (int tt = 0; tt < 4; ++tt)
            h[(m * 16 + q * 4 + tt) * 512 + col] = __logf(acc[s][tt]) + bv;
    }
}

// Layer 3 (N=256): out[row][col] = log(acc) + crow[row] + b3[col] - ln64.
// Wave W: m=W>>2, n64=W&3. Grid 256 x 64 threads.
__global__ __launch_bounds__(64) void gemm_out(const uint8_t* __restrict__ Af,
                                               const uint8_t* __restrict__ Bf,
                                               const float* __restrict__ b3,
                                               const float* __restrict__ crow,
                                               float* __restrict__ out) {
    int Wv = blockIdx.x;
    int m = Wv >> 2, n64 = Wv & 3;
    int lane = threadIdx.x;
    int r = lane & 15, q = lane >> 4;
    v4f acc[4];
    gemm_k512(Af + m * 8192 + lane * 8, Bf + lane * 8, n64 * 4, acc);
#pragma unroll
    for (int s = 0; s < 4; ++s) {
        int col = (n64 * 4 + s) * 16 + r;
        float bv = b3[col] - LN64f;
#pragma unroll
        for (int tt = 0; tt < 4; ++tt) {
            int row = m * 16 + q * 4 + tt;
            out[row * 256 + col] = __logf(acc[s][tt]) + crow[row] + bv;
        }
    }
}

// Tropical-LN: one wave per row, 8 elem/lane, zero barriers. Exact order
// stats via R9's in-register bitonic (compact runtime loops); relu; subtract
// rowmax; A = 64*exp(y-cm) scattered fp8 into next layer's fragment order.
// Grid 256 x 256 threads (4 rows/block).
__global__ __launch_bounds__(256) void ln_rows(const float* __restrict__ h,
                                               const float* __restrict__ lw,
                                               const float* __restrict__ lb,
                                               uint8_t* __restrict__ Aout,
                                               float* __restrict__ crow) {
    int w = threadIdx.x >> 6, lane = threadIdx.x & 63;
    int rho = blockIdx.x * 4 + w;                    // row 0..1023

    const float4* lw4 = reinterpret_cast<const float4*>(lw + lane * 8);
    const float4* lb4 = reinterpret_cast<const float4*>(lb + lane * 8);
    float4 wa = lw4[0], wb = lw4[1], ba = lb4[0], bbv = lb4[1];

    float hv[8], v[8];
    {
        const float* hp = h + rho * 512 + lane * 8;
        float4 a = *reinterpret_cast<const float4*>(hp);
        float4 b = *reinterpret_cast<const float4*>(hp + 4);
        hv[0] = a.x; hv[1] = a.y; hv[2] = a.z; hv[3] = a.w;
        hv[4] = b.x; hv[5] = b.y; hv[6] = b.z; hv[7] = b.w;
#pragma unroll
        for (int j = 0; j < 8; ++j) v[j] = hv[j];
    }
    // Bitonic sort of 512 values, element e = lane*8 + j, ascending.
#pragma clang loop unroll(disable)
    for (int k = 2; k <= 512; k <<= 1) {
#pragma clang loop unroll(disable)
        for (int jj = 256; jj > 0; jj >>= 1) {
            if (jj >= k) continue;
            if (jj >= 8) {
                int lm = jj >> 3;
#pragma unroll
                for (int j = 0; j < 8; ++j) {
                    float pv = __shfl_xor(v[j], lm);
                    bool up = ((((lane << 3) | j) & k) == 0);
                    bool low = ((lane & lm) == 0);
                    v[j] = (up == low) ? fminf(v[j], pv) : fmaxf(v[j], pv);
                }
            } else if (jj == 4) {
#pragma unroll
                for (int j = 0; j < 4; ++j) {
                    bool up = ((((lane << 3) | j) & k) == 0);
                    float a = v[j], c = v[j + 4];
                    float lo = fminf(a, c), hi = fmaxf(a, c);
                    v[j] = up ? lo : hi;
                    v[j + 4] = up ? hi : lo;
                }
            } else if (jj == 2) {
#pragma unroll
                for (int jb = 0; jb < 8; jb += 4)
#pragma unroll
                    for (int j0 = 0; j0 < 2; ++j0) {
                        int j = jb + j0;
                        bool up = ((((lane << 3) | j) & k) == 0);
                        float a = v[j], c = v[j + 2];
                        float lo = fminf(a, c), hi = fmaxf(a, c);
                        v[j] = up ? lo : hi;
                        v[j + 2] = up ? hi : lo;
                    }
            } else {
#pragma unroll
                for (int j = 0; j < 8; j += 2) {
                    bool up = ((((lane << 3) | j) & k) == 0);
                    float a = v[j], c = v[j + 1];
                    float lo = fminf(a, c), hi = fmaxf(a, c);
                    v[j] = up ? lo : hi;
                    v[j + 1] = up ? hi : lo;
                }
            }
        }
    }
    float s127 = __shfl(v[7], 15);
    float s128 = __shfl(v[0], 16);
    float med  = __shfl(v[7], 31);
    float s383 = __shfl(v[7], 47);
    float s384 = __shfl(v[0], 48);
    float q25 = s127 + 0.75f * (s128 - s127);
    float q75 = s383 + 0.25f * (s384 - s383);
    float inv = 1.0f / fmaxf(q75 - q25, 1e-6f);

    float y[8], cm = 0.0f;                      // y >= 0 after relu
    {
        float lwv[8] = {wa.x, wa.y, wa.z, wa.w, wb.x, wb.y, wb.z, wb.w};
        float lbv[8] = {ba.x, ba.y, ba.z, ba.w, bbv.x, bbv.y, bbv.z, bbv.w};
#pragma unroll
        for (int j = 0; j < 8; ++j) {
            y[j] = fmaxf((hv[j] - med) * inv * lwv[j] + lbv[j], 0.0f);
            cm = fmaxf(cm, y[j]);
        }
    }
#pragma unroll
    for (int s = 32; s > 0; s >>= 1) cm = fmaxf(cm, __shfl_xor(cm, s));
    {
        float e[8];
#pragma unroll
        for (int j = 0; j < 8; ++j) e[j] = 64.0f * __expf(y[j] - cm);
        int2 o;
        o.x = pk4_fp8(e[0], e[1], e[2], e[3]);
        o.y = pk4_fp8(e[4], e[5], e[6], e[7]);
        // fragment scatter: element e=lane*8+j of row rho -> k-step t=lane>>2,
        // frag lane l' = (lane&3)*16 + (rho&15)
        uint8_t* dst = Aout + ((rho >> 4) * 16 + (lane >> 2)) * 512
                            + ((lane & 3) * 16 + (rho & 15)) * 8;
        *reinterpret_cast<int2*>(dst) = o;
    }
    if (lane == 0) crow[rho] = cm;
}

extern "C" void kernel_launch(void* const* d_in, const int* in_sizes, int n_in,
                              void* d_out, int out_size, void* d_ws, size_t ws_size,
                              hipStream_t stream) {
    const float* x    = (const float*)d_in[0];
    const float* w1   = (const float*)d_in[1];
    const float* b1   = (const float*)d_in[2];
    const float* ln1w = (const float*)d_in[3];
    const float* ln1b = (const float*)d_in[4];
    const float* w2   = (const float*)d_in[5];
    const float* b2   = (const float*)d_in[6];
    const float* ln2w = (const float*)d_in[7];
    const float* ln2b = (const float*)d_in[8];
    const float* w3   = (const float*)d_in[9];
    const float* b3   = (const float*)d_in[10];
    float* out = (float*)d_out;

    uint8_t* ws = (uint8_t*)d_ws;
    uint8_t* Ew   = ws;                         // 640 KB (w1|w2|w3 fragments)
    uint8_t* A1   = ws + (1u << 20);            // 512 KB
    uint8_t* A2   = ws + (1u << 20) + 524288;   // 512 KB
    uint8_t* A3   = ws + (2u << 20);            // 512 KB
    float*   h    = (float*)(ws + (2u << 20) + 524288);  // 2 MB
    float*   crow = (float*)(ws + (5u << 20));  // 4 KB

    prep_frag<<<576, 256, 0, stream>>>(w1, w2, w3, x, Ew, A1);
    gemm_h<<<512, 64, 0, stream>>>(A1, Ew, b1, h);
    ln_rows<<<256, 256, 0, stream>>>(h, ln1w, ln1b, A2, crow);
    gemm_h<<<512, 64, 0, stream>>>(A2, Ew + 262144, b2, h);
    ln_rows<<<256, 256, 0, stream>>>(h, ln2w, ln2b, A3, crow);
    gemm_out<<<256, 64, 0, stream>>>(A3, Ew + 524288, b3, crow, out);
}

// Round 6
// 111.621 us; speedup vs baseline: 1.5040x; 1.0332x over previous
//
#include <hip/hip_runtime.h>
#include <math.h>

// ---------------------------------------------------------------------------
// TropicalMLP, R14: layered pipeline (R13) with GEMM TLP fixed.
// R13 ran gemm_h as 512 blocks x 64 threads = 1 wave/block (2 waves/CU):
// each wave is a serial 64-MFMA + 128-load latency chain, nothing to overlap.
// Now per-wave tile is 16x16 (NSUB=1): L1/L2 = 2048 waves, L3 = 1024 waves,
// packed 4 waves/block (256 thr) -> 8 waves/CU. Same total B-panel traffic,
// ~70 VGPR (allocator unconstrained -- R12 lesson: never clamp min-waves).
// Pipeline: prep (exp W1/W2/W3 + 4*exp(x), fp8, MFMA-fragment order)
//   gemm_h L1 -> ln_rows LN1 -> gemm_h L2 -> ln_rows LN2 -> gemm_out L3
// Same math/scaling as R11/R13: layer1 A=4*exp(x) (+ln4 cancels in LN1
// median); layers2/3 A=64*exp(y-cm) (+ln64-cm cancels in LN2 median /
// subtracted in final epilogue). B=exp(w) in [0.6,1.6]. prep/ln verbatim R13.
// ---------------------------------------------------------------------------

typedef float v4f __attribute__((ext_vector_type(4)));

#define LN64f 4.1588830833596715f  // ln(64)

__device__ __forceinline__ int pk4_fp8(float a, float b, float c, float d) {
    int p = __builtin_amdgcn_cvt_pk_fp8_f32(a, b, 0, 0);      // bytes 0,1
    p = __builtin_amdgcn_cvt_pk_fp8_f32(c, d, p, 1);          // bytes 2,3
    return p;
}

// prep: fp8 exp, MFMA-fragment order. 16-col tile "tile", k-step t (32 k),
// lane l=q*16+r: dst[(tile*16+t)*512 + l*8 + j] = fp8(sc*exp(M[tile*16+r][t*32+q*8+j]))
// u-space S: 0..31 w1 | 32..63 w2 | 64..79 w3 | 80..143 x (sc=4).
__global__ __launch_bounds__(256) void prep_frag(const float* __restrict__ w1,
                                                 const float* __restrict__ w2,
                                                 const float* __restrict__ w3,
                                                 const float* __restrict__ x,
                                                 uint8_t* __restrict__ Ew,
                                                 uint8_t* __restrict__ Ax) {
    int u = blockIdx.x * 256 + threadIdx.x;          // 0..147455 (576 blocks)
    int lane = u & 63, t = (u >> 6) & 15, S = u >> 10;
    int r = lane & 15, q = lane >> 4;
    const float* m; int tile; uint8_t* dst; float sc;
    if (S < 32)      { m = w1; tile = S;      dst = Ew;          sc = 1.0f; }
    else if (S < 64) { m = w2; tile = S - 32; dst = Ew + 262144; sc = 1.0f; }
    else if (S < 80) { m = w3; tile = S - 64; dst = Ew + 524288; sc = 1.0f; }
    else             { m = x;  tile = S - 80; dst = Ax;          sc = 4.0f; }
    const float* src = m + (tile * 16 + r) * 512 + t * 32 + q * 8;
    float4 a = *reinterpret_cast<const float4*>(src);
    float4 b = *reinterpret_cast<const float4*>(src + 4);
    int2 o;
    o.x = pk4_fp8(sc * __expf(a.x), sc * __expf(a.y),
                  sc * __expf(a.z), sc * __expf(a.w));
    o.y = pk4_fp8(sc * __expf(b.x), sc * __expf(b.y),
                  sc * __expf(b.z), sc * __expf(b.w));
    *reinterpret_cast<int2*>(dst + (tile * 16 + t) * 512 + lane * 8) = o;
}

// One wave: C[16 rows x 16 cols] over K=512, fp8 MFMA, rolling depth-8 B
// prefetch. ap = Af + m*8192 + lane*8, bp = Bf + n16*8192 + lane*8.
__device__ __forceinline__ v4f gemm_k512_1(const uint8_t* __restrict__ ap,
                                           const uint8_t* __restrict__ bp) {
    long areg[16];
    long bb[8];
#pragma unroll
    for (int t = 0; t < 16; ++t)
        areg[t] = *reinterpret_cast<const long*>(ap + t * 512);
#pragma unroll
    for (int p = 0; p < 8; ++p)
        bb[p] = *reinterpret_cast<const long*>(bp + p * 512);
    v4f acc = (v4f){0.f, 0.f, 0.f, 0.f};
#pragma unroll
    for (int t = 0; t < 16; ++t) {
        long a = areg[t];
        long bcur = bb[t & 7];
        if (t < 8)
            bb[t & 7] = *reinterpret_cast<const long*>(bp + (t + 8) * 512);
        acc = __builtin_amdgcn_mfma_f32_16x16x32_fp8_fp8(a, bcur, acc, 0, 0, 0);
    }
    return acc;
}

// Layers 1/2: h[row][col] = log(acc) + bias[col].  Wave W = blk*4+warp:
// m = W>>5 (M-tile 0..63), n16 = W&31 (16-col group). Grid 512 x 256.
__global__ __launch_bounds__(256) void gemm_h(const uint8_t* __restrict__ Af,
                                              const uint8_t* __restrict__ Bf,
                                              const float* __restrict__ bias,
                                              float* __restrict__ h) {
    int W = blockIdx.x * 4 + (threadIdx.x >> 6);
    int lane = threadIdx.x & 63;
    int m = W >> 5, n16 = W & 31;
    int r = lane & 15, q = lane >> 4;
    v4f acc = gemm_k512_1(Af + m * 8192 + lane * 8,
                          Bf + n16 * 8192 + lane * 8);
    int col = n16 * 16 + r;
    float bv = bias[col];
#pragma unroll
    for (int tt = 0; tt < 4; ++tt)
        h[(m * 16 + q * 4 + tt) * 512 + col] = __logf(acc[tt]) + bv;
}

// Layer 3 (N=256): out[row][col] = log(acc) + crow[row] + b3[col] - ln64.
// Wave W: m = W>>4, n16 = W&15. Grid 256 x 256.
__global__ __launch_bounds__(256) void gemm_out(const uint8_t* __restrict__ Af,
                                                const uint8_t* __restrict__ Bf,
                                                const float* __restrict__ b3,
                                                const float* __restrict__ crow,
                                                float* __restrict__ out) {
    int W = blockIdx.x * 4 + (threadIdx.x >> 6);
    int lane = threadIdx.x & 63;
    int m = W >> 4, n16 = W & 15;
    int r = lane & 15, q = lane >> 4;
    v4f acc = gemm_k512_1(Af + m * 8192 + lane * 8,
                          Bf + n16 * 8192 + lane * 8);
    int col = n16 * 16 + r;
    float bv = b3[col] - LN64f;
#pragma unroll
    for (int tt = 0; tt < 4; ++tt) {
        int row = m * 16 + q * 4 + tt;
        out[row * 256 + col] = __logf(acc[tt]) + crow[row] + bv;
    }
}

// Tropical-LN: one wave per row, 8 elem/lane, zero barriers. Exact order
// stats via in-register bitonic (compact runtime loops); relu; subtract
// rowmax; A = 64*exp(y-cm) scattered fp8 into next layer's fragment order.
// Grid 256 x 256 threads (4 rows/block).
__global__ __launch_bounds__(256) void ln_rows(const float* __restrict__ h,
                                               const float* __restrict__ lw,
                                               const float* __restrict__ lb,
                                               uint8_t* __restrict__ Aout,
                                               float* __restrict__ crow) {
    int w = threadIdx.x >> 6, lane = threadIdx.x & 63;
    int rho = blockIdx.x * 4 + w;                    // row 0..1023

    const float4* lw4 = reinterpret_cast<const float4*>(lw + lane * 8);
    const float4* lb4 = reinterpret_cast<const float4*>(lb + lane * 8);
    float4 wa = lw4[0], wb = lw4[1], ba = lb4[0], bbv = lb4[1];

    float hv[8], v[8];
    {
        const float* hp = h + rho * 512 + lane * 8;
        float4 a = *reinterpret_cast<const float4*>(hp);
        float4 b = *reinterpret_cast<const float4*>(hp + 4);
        hv[0] = a.x; hv[1] = a.y; hv[2] = a.z; hv[3] = a.w;
        hv[4] = b.x; hv[5] = b.y; hv[6] = b.z; hv[7] = b.w;
#pragma unroll
        for (int j = 0; j < 8; ++j) v[j] = hv[j];
    }
    // Bitonic sort of 512 values, element e = lane*8 + j, ascending.
#pragma clang loop unroll(disable)
    for (int k = 2; k <= 512; k <<= 1) {
#pragma clang loop unroll(disable)
        for (int jj = 256; jj > 0; jj >>= 1) {
            if (jj >= k) continue;
            if (jj >= 8) {
                int lm = jj >> 3;
#pragma unroll
                for (int j = 0; j < 8; ++j) {
                    float pv = __shfl_xor(v[j], lm);
                    bool up = ((((lane << 3) | j) & k) == 0);
                    bool low = ((lane & lm) == 0);
                    v[j] = (up == low) ? fminf(v[j], pv) : fmaxf(v[j], pv);
                }
            } else if (jj == 4) {
#pragma unroll
                for (int j = 0; j < 4; ++j) {
                    bool up = ((((lane << 3) | j) & k) == 0);
                    float a = v[j], c = v[j + 4];
                    float lo = fminf(a, c), hi = fmaxf(a, c);
                    v[j] = up ? lo : hi;
                    v[j + 4] = up ? hi : lo;
                }
            } else if (jj == 2) {
#pragma unroll
                for (int jb = 0; jb < 8; jb += 4)
#pragma unroll
                    for (int j0 = 0; j0 < 2; ++j0) {
                        int j = jb + j0;
                        bool up = ((((lane << 3) | j) & k) == 0);
                        float a = v[j], c = v[j + 2];
                        float lo = fminf(a, c), hi = fmaxf(a, c);
                        v[j] = up ? lo : hi;
                        v[j + 2] = up ? hi : lo;
                    }
            } else {
#pragma unroll
                for (int j = 0; j < 8; j += 2) {
                    bool up = ((((lane << 3) | j) & k) == 0);
                    float a = v[j], c = v[j + 1];
                    float lo = fminf(a, c), hi = fmaxf(a, c);
                    v[j] = up ? lo : hi;
                    v[j + 1] = up ? hi : lo;
                }
            }
        }
    }
    float s127 = __shfl(v[7], 15);
    float s128 = __shfl(v[0], 16);
    float med  = __shfl(v[7], 31);
    float s383 = __shfl(v[7], 47);
    float s384 = __shfl(v[0], 48);
    float q25 = s127 + 0.75f * (s128 - s127);
    float q75 = s383 + 0.25f * (s384 - s383);
    float inv = 1.0f / fmaxf(q75 - q25, 1e-6f);

    float y[8], cm = 0.0f;                      // y >= 0 after relu
    {
        float lwv[8] = {wa.x, wa.y, wa.z, wa.w, wb.x, wb.y, wb.z, wb.w};
        float lbv[8] = {ba.x, ba.y, ba.z, ba.w, bbv.x, bbv.y, bbv.z, bbv.w};
#pragma unroll
        for (int j = 0; j < 8; ++j) {
            y[j] = fmaxf((hv[j] - med) * inv * lwv[j] + lbv[j], 0.0f);
            cm = fmaxf(cm, y[j]);
        }
    }
#pragma unroll
    for (int s = 32; s > 0; s >>= 1) cm = fmaxf(cm, __shfl_xor(cm, s));
    {
        float e[8];
#pragma unroll
        for (int j = 0; j < 8; ++j) e[j] = 64.0f * __expf(y[j] - cm);
        int2 o;
        o.x = pk4_fp8(e[0], e[1], e[2], e[3]);
        o.y = pk4_fp8(e[4], e[5], e[6], e[7]);
        // fragment scatter: element e=lane*8+j of row rho -> k-step t=lane>>2,
        // frag lane l' = (lane&3)*16 + (rho&15)
        uint8_t* dst = Aout + ((rho >> 4) * 16 + (lane >> 2)) * 512
                            + ((lane & 3) * 16 + (rho & 15)) * 8;
        *reinterpret_cast<int2*>(dst) = o;
    }
    if (lane == 0) crow[rho] = cm;
}

extern "C" void kernel_launch(void* const* d_in, const int* in_sizes, int n_in,
                              void* d_out, int out_size, void* d_ws, size_t ws_size,
                              hipStream_t stream) {
    const float* x    = (const float*)d_in[0];
    const float* w1   = (const float*)d_in[1];
    const float* b1   = (const float*)d_in[2];
    const float* ln1w = (const float*)d_in[3];
    const float* ln1b = (const float*)d_in[4];
    const float* w2   = (const float*)d_in[5];
    const float* b2   = (const float*)d_in[6];
    const float* ln2w = (const float*)d_in[7];
    const float* ln2b = (const float*)d_in[8];
    const float* w3   = (const float*)d_in[9];
    const float* b3   = (const float*)d_in[10];
    float* out = (float*)d_out;

    uint8_t* ws = (uint8_t*)d_ws;
    uint8_t* Ew   = ws;                         // 640 KB (w1|w2|w3 fragments)
    uint8_t* A1   = ws + (1u << 20);            // 512 KB
    uint8_t* A2   = ws + (1u << 20) + 524288;   // 512 KB
    uint8_t* A3   = ws + (2u << 20);            // 512 KB
    float*   h    = (float*)(ws + (2u << 20) + 524288);  // 2 MB
    float*   crow = (float*)(ws + (5u << 20));  // 4 KB

    prep_frag<<<576, 256, 0, stream>>>(w1, w2, w3, x, Ew, A1);
    gemm_h<<<512, 256, 0, stream>>>(A1, Ew, b1, h);
    ln_rows<<<256, 256, 0, stream>>>(h, ln1w, ln1b, A2, crow);
    gemm_h<<<512, 256, 0, stream>>>(A2, Ew + 262144, b2, h);
    ln_rows<<<256, 256, 0, stream>>>(h, ln2w, ln2b, A3, crow);
    gemm_out<<<256, 256, 0, stream>>>(A3, Ew + 524288, b3, crow, out);
}